// Round 4
// baseline (602.257 us; speedup 1.0000x reference)
//
#include <hip/hip_runtime.h>
#include <hip/hip_bf16.h>
#include <math.h>

// ---------- types ----------
typedef __attribute__((ext_vector_type(8))) short s8vec;     // 8 x bf16 bits (4 VGPRs)
typedef __attribute__((ext_vector_type(16))) float f32x16;   // 32x32 MFMA C/D
typedef __attribute__((ext_vector_type(4))) unsigned short us4;

__device__ __forceinline__ unsigned short f2bf(float f) {
  unsigned u = __float_as_uint(f);
  u = (u + 0x7fffu + ((u >> 16) & 1u)) >> 16;   // RNE
  return (unsigned short)u;
}
__device__ __forceinline__ float bf2f(unsigned short u) {
  return __uint_as_float(((unsigned)u) << 16);
}

// fast gelu: t * sigmoid(1.5957691t + 0.07135481t^3); |err vs erf-gelu| < 3e-3
__device__ __forceinline__ float fast_gelu(float t) {
  float t2 = t * t;
  float u = t * (1.59576912f + 0.07135481f * t2);
  float e = __expf(-u);
  return t * __frcp_rn(1.0f + e);
}

// async global->LDS, 16B per lane. LDS dest = wave-uniform base + lane*16.
__device__ __forceinline__ void async_ld16(const unsigned short* g, unsigned short* l) {
  __builtin_amdgcn_global_load_lds(
      (__attribute__((address_space(1))) void*)g,
      (__attribute__((address_space(3))) void*)l, 16, 0, 0);
}

// ---------- generic NT GEMM: C[M,N] = A[M,K] * Bt[N,K]^T ----------
// 128x128 tile, BK=64. FRAGMENT-ORDER LDS: As/Bs are 16 groups x 1KB; group
// (h, i, s) holds the exact 64-lane MFMA fragment (lane l -> row h*64+i*32+
// (l&31), k-chunk s*16+(l>>5)*8). Staging lane l of issue (h,i,s) fetches
// that element directly, so both the DMA write AND the ds_read_b128 are
// lane-contiguous 1KB blocks: bank-conflict-free by construction, and all
// inner-loop addresses are base + immediate.
// 4 waves, each 64x64 via 2x2 mfma_f32_32x32x16_bf16.
// C/D: col=lane&31, row=(reg&3)+8*(reg>>2)+4*(lane>>5).
// EPI: 0 = out_bf16 = acc*scale          (scores)
//      1 = out_f32 = acc + res           (attn + residual -> x)
//      2 = out_bf16 = gelu(acc + bias)   (FFN1)
//      3 = out_f32 = acc + bias + res    (FFN2 + residual)
template <int EPI>
__global__ __launch_bounds__(256) void gemm_nt(
    const unsigned short* __restrict__ A, const unsigned short* __restrict__ B,
    float* __restrict__ outF, unsigned short* __restrict__ outB,
    const float* __restrict__ bias, const float* __restrict__ res,
    int M, int N, int K,
    long long bA, long long bB, long long bO, long long bR, float scale)
{
  __shared__ __align__(16) unsigned short As[16 * 512];   // 16 KiB
  __shared__ __align__(16) unsigned short Bs[16 * 512];   // 16 KiB

  const int tid = threadIdx.x;
  const int w = tid >> 6;        // wave 0..3
  const int l = tid & 63;        // lane
  const int z = blockIdx.z;

  A += (size_t)z * bA;
  B += (size_t)z * bB;

  const size_t tileM = (size_t)blockIdx.y * 128;
  const size_t tileN = (size_t)blockIdx.x * 128;

  // staging assignment: wave w stages A groups (hA=w&1, iA=w>>1, s=0..3)
  // and B groups (hB=w>>1, jB=w&1, s=0..3). Lane l of issue s fetches
  // row = h*64 + i*32 + (l&31), elements [s*16 + (l>>5)*8, +8).
  const int hA = w & 1, iA = w >> 1;
  const int hB = w >> 1, jB = w & 1;
  const unsigned short* aSrc = A + (tileM + (hA << 6) + (iA << 5) + (l & 31)) * (size_t)K + ((l >> 5) << 3);
  const unsigned short* bSrc = B + (tileN + (hB << 6) + (jB << 5) + (l & 31)) * (size_t)K + ((l >> 5) << 3);
  unsigned short* aDst = &As[(((hA << 1) | iA) << 2) * 512];
  unsigned short* bDst = &Bs[(((hB << 1) | jB) << 2) * 512];

  // compute mapping: waves 2x2; wave reads A half (w>>1), B half (w&1)
  const int wmh = w >> 1;
  const int wnh = w & 1;
  const unsigned short* aRd = &As[(wmh << 12) + (l << 3)];
  const unsigned short* bRd = &Bs[(wnh << 12) + (l << 3)];
  const int fr = l & 31;    // C/D col field
  const int fq = l >> 5;

  f32x16 acc[2][2] = {};

  for (int k0 = 0; k0 < K; k0 += 64) {
    __syncthreads();                 // previous tile fully consumed
#pragma unroll
    for (int s = 0; s < 4; ++s) {
      async_ld16(aSrc + k0 + (s << 4), aDst + (s << 9));
      async_ld16(bSrc + k0 + (s << 4), bDst + (s << 9));
    }
    __syncthreads();                 // drain loads

#pragma unroll
    for (int s = 0; s < 4; ++s) {
      s8vec af[2], bf[2];
#pragma unroll
      for (int i = 0; i < 2; ++i)
        af[i] = *(const s8vec*)(aRd + (((i << 2) + s) << 9));
#pragma unroll
      for (int j = 0; j < 2; ++j)
        bf[j] = *(const s8vec*)(bRd + (((j << 2) + s) << 9));
#pragma unroll
      for (int i = 0; i < 2; ++i)
#pragma unroll
        for (int j = 0; j < 2; ++j)
          acc[i][j] = __builtin_amdgcn_mfma_f32_32x32x16_bf16(af[i], bf[j], acc[i][j], 0, 0, 0);
    }
  }

  // epilogue. C/D: col = lane&31, row = (reg&3) + 8*(reg>>2) + 4*(lane>>5)
  float* oF = outF + (size_t)z * bO;
  unsigned short* oB = outB + (size_t)z * bO;
  const float* rs = res + (size_t)z * bR;
  const int wm = wmh << 6, wn = wnh << 6;

  float bcol[2];
  if (EPI >= 2) {
#pragma unroll
    for (int j = 0; j < 2; ++j) bcol[j] = bias[tileN + wn + (j << 5) + fr];
  }

#pragma unroll
  for (int i = 0; i < 2; ++i) {
#pragma unroll
    for (int r = 0; r < 16; ++r) {
      const size_t row = tileM + wm + (i << 5) + (r & 3) + ((r >> 2) << 3) + (fq << 2);
      const size_t rb = row * (size_t)N;
#pragma unroll
      for (int j = 0; j < 2; ++j) {
        const size_t col = tileN + wn + (j << 5) + fr;
        const float v = acc[i][j][r];
        if (EPI == 0) {
          oB[rb + col] = f2bf(v * scale);
        } else if (EPI == 1) {
          oF[rb + col] = v + rs[rb + col];
        } else if (EPI == 2) {
          oB[rb + col] = f2bf(fast_gelu(v + bcol[j]));
        } else {
          oF[rb + col] = v + bcol[j] + rs[rb + col];
        }
      }
    }
  }
}

// ---------- LayerNorm over rows of 1024 fp32 -> bf16 ----------
__global__ __launch_bounds__(256) void ln_row(
    const float* __restrict__ x, const float* __restrict__ gamma,
    const float* __restrict__ beta, unsigned short* __restrict__ out)
{
  const int row = blockIdx.x;
  const float4* xr = (const float4*)(x + (size_t)row * 1024);
  const int tid = threadIdx.x;
  float4 v = xr[tid];
  float s = v.x + v.y + v.z + v.w;
  float q = v.x * v.x + v.y * v.y + v.z * v.z + v.w * v.w;
#pragma unroll
  for (int off = 32; off > 0; off >>= 1) {
    s += __shfl_down(s, off);
    q += __shfl_down(q, off);
  }
  __shared__ float rs_[4], rq_[4];
  const int w = tid >> 6, l = tid & 63;
  if (l == 0) { rs_[w] = s; rq_[w] = q; }
  __syncthreads();
  s = rs_[0] + rs_[1] + rs_[2] + rs_[3];
  q = rq_[0] + rq_[1] + rq_[2] + rq_[3];
  const float mu = s * (1.0f / 1024.0f);
  const float var = q * (1.0f / 1024.0f) - mu * mu;
  const float rstd = rsqrtf(var + 1e-5f);
  const float4 g = ((const float4*)gamma)[tid];
  const float4 b = ((const float4*)beta)[tid];
  us4 o;
  o.x = f2bf((v.x - mu) * rstd * g.x + b.x);
  o.y = f2bf((v.y - mu) * rstd * g.y + b.y);
  o.z = f2bf((v.z - mu) * rstd * g.z + b.z);
  o.w = f2bf((v.w - mu) * rstd * g.w + b.w);
  ((us4*)(out + (size_t)row * 1024))[tid] = o;
}

// ---------- softmax over rows of 2048 bf16 -> bf16 ----------
__global__ __launch_bounds__(256) void softmax_row(
    const unsigned short* __restrict__ sc, unsigned short* __restrict__ pr)
{
  const int row = blockIdx.x;
  const s8vec* s8 = (const s8vec*)(sc + (size_t)row * 2048);
  const int tid = threadIdx.x;
  s8vec a = s8[tid];                 // 8 bf16
  float x[8];
#pragma unroll
  for (int i = 0; i < 8; ++i) x[i] = bf2f((unsigned short)a[i]);
  float mx = x[0];
#pragma unroll
  for (int i = 1; i < 8; ++i) mx = fmaxf(mx, x[i]);
#pragma unroll
  for (int off = 32; off > 0; off >>= 1) mx = fmaxf(mx, __shfl_down(mx, off));
  __shared__ float red[4];
  const int w = tid >> 6, l = tid & 63;
  if (l == 0) red[w] = mx;
  __syncthreads();
  mx = fmaxf(fmaxf(red[0], red[1]), fmaxf(red[2], red[3]));
  __syncthreads();
  float e[8], s = 0.f;
#pragma unroll
  for (int i = 0; i < 8; ++i) { e[i] = __expf(x[i] - mx); s += e[i]; }
#pragma unroll
  for (int off = 32; off > 0; off >>= 1) s += __shfl_down(s, off);
  if (l == 0) red[w] = s;
  __syncthreads();
  s = red[0] + red[1] + red[2] + red[3];
  const float inv = 1.0f / s;
  s8vec o;
#pragma unroll
  for (int i = 0; i < 8; ++i) o[i] = (short)f2bf(e[i] * inv);
  ((s8vec*)(pr + (size_t)row * 2048))[tid] = o;
}

// ---------- transpose + convert to bf16: in[R,C] -> out[C,R] ----------
template <bool BF16IN>
__global__ __launch_bounds__(256) void transpose_conv(
    const void* __restrict__ in_, unsigned short* __restrict__ out,
    int R, int C, long long bIn, long long bOut)
{
  __shared__ float tile[32][33];
  const int z = blockIdx.z;
  const int tx = threadIdx.x, ty = threadIdx.y;   // block (32,8)
  const int c0 = blockIdx.x * 32, r0 = blockIdx.y * 32;
  if (BF16IN) {
    const unsigned short* in = (const unsigned short*)in_ + (size_t)z * bIn;
    for (int i = ty; i < 32; i += 8)
      tile[i][tx] = bf2f(in[(size_t)(r0 + i) * C + c0 + tx]);
  } else {
    const float* in = (const float*)in_ + (size_t)z * bIn;
    for (int i = ty; i < 32; i += 8)
      tile[i][tx] = in[(size_t)(r0 + i) * C + c0 + tx];
  }
  __syncthreads();
  unsigned short* o = out + (size_t)z * bOut;
  for (int i = ty; i < 32; i += 8)
    o[(size_t)(c0 + i) * R + r0 + tx] = f2bf(tile[tx][i]);
}

// ---------- launch ----------
extern "C" void kernel_launch(void* const* d_in, const int* in_sizes, int n_in,
                              void* d_out, int out_size, void* d_ws, size_t ws_size,
                              hipStream_t stream)
{
  (void)in_sizes; (void)n_in; (void)out_size; (void)ws_size;
  const float* src = (const float*)d_in[0];
  const float* g1  = (const float*)d_in[1];
  const float* be1 = (const float*)d_in[2];
  const float* g2  = (const float*)d_in[3];
  const float* be2 = (const float*)d_in[4];
  const float* w1  = (const float*)d_in[5];
  const float* b1  = (const float*)d_in[6];
  const float* w2  = (const float*)d_in[7];
  const float* b2  = (const float*)d_in[8];
  float* out = (float*)d_out;

  // workspace layout (bytes). Peak = 184,549,376.
  char* ws = (char*)d_ws;
  const size_t SZ_NORMX  = (size_t)8192 * 1024 * 2;     // 16 MiB
  const size_t SZ_SCORES = (size_t)4 * 2048 * 2048 * 4; // 64 MiB region (scores bf16 uses half; hbuf uses all)
  const size_t SZ_PROBS  = (size_t)4 * 2048 * 2048 * 2; // 32 MiB
  const size_t SZ_X      = (size_t)8192 * 1024 * 4;     // 32 MiB
  const size_t SZ_W1T    = (size_t)1024 * 4096 * 2;     // 8 MiB

  unsigned short* normx  = (unsigned short*)(ws);
  unsigned short* normxT = (unsigned short*)(ws + SZ_NORMX);
  unsigned short* scores = (unsigned short*)(ws + 2 * SZ_NORMX);
  unsigned short* probs  = (unsigned short*)(ws + 2 * SZ_NORMX + SZ_SCORES);
  float*          xbuf   = (float*)(ws + 2 * SZ_NORMX + SZ_SCORES + SZ_PROBS);
  unsigned short* w1t    = (unsigned short*)(ws + 2 * SZ_NORMX + SZ_SCORES + SZ_PROBS + SZ_X);
  unsigned short* w2t    = (unsigned short*)(ws + 2 * SZ_NORMX + SZ_SCORES + SZ_PROBS + SZ_X + SZ_W1T);
  unsigned short* normx2 = normx;                       // reuse (dead after attn)
  unsigned short* hbuf   = scores;                      // reuse (dead after softmax)

  const dim3 tb(32, 8);
  // weights fp32 -> bf16 transposed (every call; ws is re-poisoned)
  transpose_conv<false><<<dim3(128, 32, 1), tb, 0, stream>>>(w1, w1t, 1024, 4096, 0, 0);
  transpose_conv<false><<<dim3(32, 128, 1), tb, 0, stream>>>(w2, w2t, 4096, 1024, 0, 0);

  // LN1
  ln_row<<<8192, 256, 0, stream>>>(src, g1, be1, normx);
  // normx^T per batch (for PV as NT)
  transpose_conv<true><<<dim3(32, 64, 4), tb, 0, stream>>>(
      normx, normxT, 2048, 1024, (long long)2048 * 1024, (long long)1024 * 2048);

  // scores = bf16(normx . normx^T / 32)
  gemm_nt<0><<<dim3(16, 16, 4), 256, 0, stream>>>(
      normx, normx, nullptr, scores, nullptr, nullptr,
      2048, 2048, 1024,
      (long long)2048 * 1024, (long long)2048 * 1024, (long long)2048 * 2048, 0, 0.03125f);

  // softmax rows (bf16 in/out)
  softmax_row<<<8192, 256, 0, stream>>>(scores, probs);

  // x = probs . normx + src
  gemm_nt<1><<<dim3(8, 16, 4), 256, 0, stream>>>(
      probs, normxT, xbuf, nullptr, nullptr, src,
      2048, 1024, 2048,
      (long long)2048 * 2048, (long long)1024 * 2048, (long long)2048 * 1024,
      (long long)2048 * 1024, 1.0f);

  // LN2
  ln_row<<<8192, 256, 0, stream>>>(xbuf, g2, be2, normx2);

  // h = gelu(normx2 . w1 + b1)
  gemm_nt<2><<<dim3(32, 64, 1), 256, 0, stream>>>(
      normx2, w1t, nullptr, hbuf, b1, nullptr,
      8192, 4096, 1024, 0, 0, 0, 0, 1.0f);

  // out = h . w2 + b2 + x
  gemm_nt<3><<<dim3(8, 64, 1), 256, 0, stream>>>(
      hbuf, w2t, out, nullptr, b2, xbuf,
      8192, 1024, 4096, 0, 0, 0, 0, 1.0f);
}

// Round 5
// 430.228 us; speedup vs baseline: 1.3999x; 1.3999x over previous
//
#include <hip/hip_runtime.h>
#include <hip/hip_bf16.h>
#include <math.h>

// ---------- types ----------
typedef __attribute__((ext_vector_type(8))) short s8vec;     // 8 x bf16 bits (4 VGPRs)
typedef __attribute__((ext_vector_type(16))) float f32x16;   // 32x32 MFMA C/D
typedef __attribute__((ext_vector_type(4))) unsigned short us4;

__device__ __forceinline__ unsigned short f2bf(float f) {
  unsigned u = __float_as_uint(f);
  u = (u + 0x7fffu + ((u >> 16) & 1u)) >> 16;   // RNE
  return (unsigned short)u;
}
__device__ __forceinline__ float bf2f(unsigned short u) {
  return __uint_as_float(((unsigned)u) << 16);
}

// fast gelu: t * sigmoid(1.5957691t + 0.07135481t^3); |err vs erf-gelu| < 3e-3
__device__ __forceinline__ float fast_gelu(float t) {
  float t2 = t * t;
  float u = t * (1.59576912f + 0.07135481f * t2);
  float e = __expf(-u);
  return t * __frcp_rn(1.0f + e);
}

// async global->LDS, 16B per lane. LDS dest = wave-uniform base + lane*16.
__device__ __forceinline__ void async_ld16(const unsigned short* g, unsigned short* l) {
  __builtin_amdgcn_global_load_lds(
      (__attribute__((address_space(1))) void*)g,
      (__attribute__((address_space(3))) void*)l, 16, 0, 0);
}

// ---------- generic NT GEMM: C[M,N] = A[M,K] * Bt[N,K]^T ----------
// 128x128 tile, BK=64, row-major LDS (row stride 128 B) with 2-axis XOR
// swizzle: logical 16B chunk c of row r lives at phys chunk c ^ (r&7) ^
// ((r>>3)&3). This keeps global staging row-contiguous (coalesced, FETCH ~=
// ideal) AND makes ds_read_b128 fragment reads <=2-way on every possible
// HW phase grouping (2-way is free on gfx950 — m136). Round 3's r&7-only
// swizzle was 4-way under interleaved-by-8 phasing (8.4M conflict cycles).
// 4 waves, each 64x64 via 2x2 mfma_f32_32x32x16_bf16.
// C/D: col=lane&31, row=(reg&3)+8*(reg>>2)+4*(lane>>5).
// EPI: 0 = out_bf16 = acc*scale          (scores)
//      1 = out_f32 = acc + res           (attn + residual -> x)
//      2 = out_bf16 = gelu(acc + bias)   (FFN1)
//      3 = out_f32 = acc + bias + res    (FFN2 + residual)
template <int EPI>
__global__ __launch_bounds__(256) void gemm_nt(
    const unsigned short* __restrict__ A, const unsigned short* __restrict__ B,
    float* __restrict__ outF, unsigned short* __restrict__ outB,
    const float* __restrict__ bias, const float* __restrict__ res,
    int M, int N, int K,
    long long bA, long long bB, long long bO, long long bR, float scale)
{
  __shared__ __align__(16) unsigned short As[128 * 64];   // 16 KiB
  __shared__ __align__(16) unsigned short Bs[128 * 64];   // 16 KiB

  const int tid = threadIdx.x;
  const int w = tid >> 6;        // wave 0..3
  const int l = tid & 63;        // lane
  const int z = blockIdx.z;

  A += (size_t)z * bA;
  B += (size_t)z * bB;

  const size_t tileM = (size_t)blockIdx.y * 128;
  const size_t tileN = (size_t)blockIdx.x * 128;

  // ---- staging: wave w stages rows [w*32, w*32+32) of A and B in 4 issues
  // of 8 rows x 128 B. Lane l -> phys slot (row = l>>3, chunk = l&7); issue i
  // covers global rows w*32+i*8+ (l>>3), so f(r) = (l>>3) ^ i, and the lane
  // fetches logical chunk (l&7) ^ (l>>3) ^ i. Each 8-lane run still permutes
  // a full 128-B row -> coalesced.
  const int sRow = l >> 3;
  const unsigned short* aP[4];
  const unsigned short* bP[4];
#pragma unroll
  for (int i = 0; i < 4; ++i) {
    const int c = (l & 7) ^ sRow ^ i;
    aP[i] = A + (tileM + (w << 5) + (i << 3) + sRow) * (size_t)K + (c << 3);
    bP[i] = B + (tileN + (w << 5) + (i << 3) + sRow) * (size_t)K + (c << 3);
  }
  unsigned short* ldsA = &As[(w << 5) * 64];
  unsigned short* ldsB = &Bs[(w << 5) * 64];

  // compute mapping: waves 2x2, wave tile origin (wm, wn)
  const int wm = (w >> 1) << 6;
  const int wn = (w & 1) << 6;
  const int fr = l & 31;    // A row / B col within 32
  const int fq = l >> 5;    // K-half (0..1)
  const int swz = (l & 7) ^ ((l >> 3) & 3);   // f(row) as seen by this lane
  const int aRow = (wm + fr) * 64;
  const int bRow = (wn + fr) * 64;

  f32x16 acc[2][2] = {};

  for (int k0 = 0; k0 < K; k0 += 64) {
    __syncthreads();                 // previous tile fully consumed
#pragma unroll
    for (int i = 0; i < 4; ++i) {
      async_ld16(aP[i] + k0, ldsA + (i << 3) * 64);
      async_ld16(bP[i] + k0, ldsB + (i << 3) * 64);
    }
    __syncthreads();                 // drain loads

#pragma unroll
    for (int s = 0; s < 4; ++s) {          // 4 K-steps of 16
      const int p = ((s << 1) + fq) ^ swz; // swizzled 16B chunk
      s8vec af[2], bf[2];
#pragma unroll
      for (int i = 0; i < 2; ++i)
        af[i] = *(const s8vec*)&As[aRow + (i << 11) + (p << 3)];
#pragma unroll
      for (int j = 0; j < 2; ++j)
        bf[j] = *(const s8vec*)&Bs[bRow + (j << 11) + (p << 3)];
#pragma unroll
      for (int i = 0; i < 2; ++i)
#pragma unroll
        for (int j = 0; j < 2; ++j)
          acc[i][j] = __builtin_amdgcn_mfma_f32_32x32x16_bf16(af[i], bf[j], acc[i][j], 0, 0, 0);
    }
  }

  // epilogue. C/D: col = lane&31, row = (reg&3) + 8*(reg>>2) + 4*(lane>>5)
  float* oF = outF + (size_t)z * bO;
  unsigned short* oB = outB + (size_t)z * bO;
  const float* rs = res + (size_t)z * bR;

  float bcol[2];
  if (EPI >= 2) {
#pragma unroll
    for (int j = 0; j < 2; ++j) bcol[j] = bias[tileN + wn + (j << 5) + fr];
  }

#pragma unroll
  for (int i = 0; i < 2; ++i) {
#pragma unroll
    for (int r = 0; r < 16; ++r) {
      const size_t row = tileM + wm + (i << 5) + (r & 3) + ((r >> 2) << 3) + (fq << 2);
      const size_t rb = row * (size_t)N;
#pragma unroll
      for (int j = 0; j < 2; ++j) {
        const size_t col = tileN + wn + (j << 5) + fr;
        const float v = acc[i][j][r];
        if (EPI == 0) {
          oB[rb + col] = f2bf(v * scale);
        } else if (EPI == 1) {
          oF[rb + col] = v + rs[rb + col];
        } else if (EPI == 2) {
          oB[rb + col] = f2bf(fast_gelu(v + bcol[j]));
        } else {
          oF[rb + col] = v + bcol[j] + rs[rb + col];
        }
      }
    }
  }
}

// ---------- LayerNorm over rows of 1024 fp32 -> bf16 ----------
__global__ __launch_bounds__(256) void ln_row(
    const float* __restrict__ x, const float* __restrict__ gamma,
    const float* __restrict__ beta, unsigned short* __restrict__ out)
{
  const int row = blockIdx.x;
  const float4* xr = (const float4*)(x + (size_t)row * 1024);
  const int tid = threadIdx.x;
  float4 v = xr[tid];
  float s = v.x + v.y + v.z + v.w;
  float q = v.x * v.x + v.y * v.y + v.z * v.z + v.w * v.w;
#pragma unroll
  for (int off = 32; off > 0; off >>= 1) {
    s += __shfl_down(s, off);
    q += __shfl_down(q, off);
  }
  __shared__ float rs_[4], rq_[4];
  const int w = tid >> 6, l = tid & 63;
  if (l == 0) { rs_[w] = s; rq_[w] = q; }
  __syncthreads();
  s = rs_[0] + rs_[1] + rs_[2] + rs_[3];
  q = rq_[0] + rq_[1] + rq_[2] + rq_[3];
  const float mu = s * (1.0f / 1024.0f);
  const float var = q * (1.0f / 1024.0f) - mu * mu;
  const float rstd = rsqrtf(var + 1e-5f);
  const float4 g = ((const float4*)gamma)[tid];
  const float4 b = ((const float4*)beta)[tid];
  us4 o;
  o.x = f2bf((v.x - mu) * rstd * g.x + b.x);
  o.y = f2bf((v.y - mu) * rstd * g.y + b.y);
  o.z = f2bf((v.z - mu) * rstd * g.z + b.z);
  o.w = f2bf((v.w - mu) * rstd * g.w + b.w);
  ((us4*)(out + (size_t)row * 1024))[tid] = o;
}

// ---------- softmax over rows of 2048 bf16 -> bf16 ----------
__global__ __launch_bounds__(256) void softmax_row(
    const unsigned short* __restrict__ sc, unsigned short* __restrict__ pr)
{
  const int row = blockIdx.x;
  const s8vec* s8 = (const s8vec*)(sc + (size_t)row * 2048);
  const int tid = threadIdx.x;
  s8vec a = s8[tid];                 // 8 bf16
  float x[8];
#pragma unroll
  for (int i = 0; i < 8; ++i) x[i] = bf2f((unsigned short)a[i]);
  float mx = x[0];
#pragma unroll
  for (int i = 1; i < 8; ++i) mx = fmaxf(mx, x[i]);
#pragma unroll
  for (int off = 32; off > 0; off >>= 1) mx = fmaxf(mx, __shfl_down(mx, off));
  __shared__ float red[4];
  const int w = tid >> 6, l = tid & 63;
  if (l == 0) red[w] = mx;
  __syncthreads();
  mx = fmaxf(fmaxf(red[0], red[1]), fmaxf(red[2], red[3]));
  __syncthreads();
  float e[8], s = 0.f;
#pragma unroll
  for (int i = 0; i < 8; ++i) { e[i] = __expf(x[i] - mx); s += e[i]; }
#pragma unroll
  for (int off = 32; off > 0; off >>= 1) s += __shfl_down(s, off);
  if (l == 0) red[w] = s;
  __syncthreads();
  s = red[0] + red[1] + red[2] + red[3];
  const float inv = 1.0f / s;
  s8vec o;
#pragma unroll
  for (int i = 0; i < 8; ++i) o[i] = (short)f2bf(e[i] * inv);
  ((s8vec*)(pr + (size_t)row * 2048))[tid] = o;
}

// ---------- transpose + convert to bf16: in[R,C] -> out[C,R] ----------
template <bool BF16IN>
__global__ __launch_bounds__(256) void transpose_conv(
    const void* __restrict__ in_, unsigned short* __restrict__ out,
    int R, int C, long long bIn, long long bOut)
{
  __shared__ float tile[32][33];
  const int z = blockIdx.z;
  const int tx = threadIdx.x, ty = threadIdx.y;   // block (32,8)
  const int c0 = blockIdx.x * 32, r0 = blockIdx.y * 32;
  if (BF16IN) {
    const unsigned short* in = (const unsigned short*)in_ + (size_t)z * bIn;
    for (int i = ty; i < 32; i += 8)
      tile[i][tx] = bf2f(in[(size_t)(r0 + i) * C + c0 + tx]);
  } else {
    const float* in = (const float*)in_ + (size_t)z * bIn;
    for (int i = ty; i < 32; i += 8)
      tile[i][tx] = in[(size_t)(r0 + i) * C + c0 + tx];
  }
  __syncthreads();
  unsigned short* o = out + (size_t)z * bOut;
  for (int i = ty; i < 32; i += 8)
    o[(size_t)(c0 + i) * R + r0 + tx] = f2bf(tile[tx][i]);
}

// ---------- launch ----------
extern "C" void kernel_launch(void* const* d_in, const int* in_sizes, int n_in,
                              void* d_out, int out_size, void* d_ws, size_t ws_size,
                              hipStream_t stream)
{
  (void)in_sizes; (void)n_in; (void)out_size; (void)ws_size;
  const float* src = (const float*)d_in[0];
  const float* g1  = (const float*)d_in[1];
  const float* be1 = (const float*)d_in[2];
  const float* g2  = (const float*)d_in[3];
  const float* be2 = (const float*)d_in[4];
  const float* w1  = (const float*)d_in[5];
  const float* b1  = (const float*)d_in[6];
  const float* w2  = (const float*)d_in[7];
  const float* b2  = (const float*)d_in[8];
  float* out = (float*)d_out;

  // workspace layout (bytes). Peak = 184,549,376.
  char* ws = (char*)d_ws;
  const size_t SZ_NORMX  = (size_t)8192 * 1024 * 2;     // 16 MiB
  const size_t SZ_SCORES = (size_t)4 * 2048 * 2048 * 4; // 64 MiB region (scores bf16 uses half; hbuf uses all)
  const size_t SZ_PROBS  = (size_t)4 * 2048 * 2048 * 2; // 32 MiB
  const size_t SZ_X      = (size_t)8192 * 1024 * 4;     // 32 MiB
  const size_t SZ_W1T    = (size_t)1024 * 4096 * 2;     // 8 MiB

  unsigned short* normx  = (unsigned short*)(ws);
  unsigned short* normxT = (unsigned short*)(ws + SZ_NORMX);
  unsigned short* scores = (unsigned short*)(ws + 2 * SZ_NORMX);
  unsigned short* probs  = (unsigned short*)(ws + 2 * SZ_NORMX + SZ_SCORES);
  float*          xbuf   = (float*)(ws + 2 * SZ_NORMX + SZ_SCORES + SZ_PROBS);
  unsigned short* w1t    = (unsigned short*)(ws + 2 * SZ_NORMX + SZ_SCORES + SZ_PROBS + SZ_X);
  unsigned short* w2t    = (unsigned short*)(ws + 2 * SZ_NORMX + SZ_SCORES + SZ_PROBS + SZ_X + SZ_W1T);
  unsigned short* normx2 = normx;                       // reuse (dead after attn)
  unsigned short* hbuf   = scores;                      // reuse (dead after softmax)

  const dim3 tb(32, 8);
  // weights fp32 -> bf16 transposed (every call; ws is re-poisoned)
  transpose_conv<false><<<dim3(128, 32, 1), tb, 0, stream>>>(w1, w1t, 1024, 4096, 0, 0);
  transpose_conv<false><<<dim3(32, 128, 1), tb, 0, stream>>>(w2, w2t, 4096, 1024, 0, 0);

  // LN1
  ln_row<<<8192, 256, 0, stream>>>(src, g1, be1, normx);
  // normx^T per batch (for PV as NT)
  transpose_conv<true><<<dim3(32, 64, 4), tb, 0, stream>>>(
      normx, normxT, 2048, 1024, (long long)2048 * 1024, (long long)1024 * 2048);

  // scores = bf16(normx . normx^T / 32)
  gemm_nt<0><<<dim3(16, 16, 4), 256, 0, stream>>>(
      normx, normx, nullptr, scores, nullptr, nullptr,
      2048, 2048, 1024,
      (long long)2048 * 1024, (long long)2048 * 1024, (long long)2048 * 2048, 0, 0.03125f);

  // softmax rows (bf16 in/out)
  softmax_row<<<8192, 256, 0, stream>>>(scores, probs);

  // x = probs . normx + src
  gemm_nt<1><<<dim3(8, 16, 4), 256, 0, stream>>>(
      probs, normxT, xbuf, nullptr, nullptr, src,
      2048, 1024, 2048,
      (long long)2048 * 2048, (long long)1024 * 2048, (long long)2048 * 1024,
      (long long)2048 * 1024, 1.0f);

  // LN2
  ln_row<<<8192, 256, 0, stream>>>(xbuf, g2, be2, normx2);

  // h = gelu(normx2 . w1 + b1)
  gemm_nt<2><<<dim3(32, 64, 1), 256, 0, stream>>>(
      normx2, w1t, nullptr, hbuf, b1, nullptr,
      8192, 4096, 1024, 0, 0, 0, 0, 1.0f);

  // out = h . w2 + b2 + x
  gemm_nt<3><<<dim3(8, 64, 1), 256, 0, stream>>>(
      hbuf, w2t, out, nullptr, b2, xbuf,
      8192, 1024, 4096, 0, 0, 0, 0, 1.0f);
}